// Round 4
// baseline (219.085 us; speedup 1.0000x reference)
//
#include <hip/hip_runtime.h>
#include <hip/hip_bf16.h>
#include <stdint.h>

typedef __bf16 bf16;
typedef __bf16 bf16x8 __attribute__((ext_vector_type(8)));
typedef __bf16 bf16x4 __attribute__((ext_vector_type(4)));
typedef float f32x4 __attribute__((ext_vector_type(4)));

#define N_TOK 4096
#define DDIM 1024
#define HDIM 2048
#define NPAIR 8192
#define BM 256
#define BN 128
#define BK 32
#define MTILES 39  // worst-case sum_e ceil(cnt_e/256) = 32 + 7

__device__ __forceinline__ void gload16(const void* g, void* l) {
  __builtin_amdgcn_global_load_lds(
      (const __attribute__((address_space(1))) unsigned int*)g,
      (__attribute__((address_space(3))) unsigned int*)l, 16, 0, 0);
}

// ------- per-expert transpose+convert: in [R][C] f32 -> out [C][R] bf16 -------
__global__ void transpose_cvt_kernel(const float* __restrict__ in, bf16* __restrict__ out,
                                     int R, int C) {
  __shared__ float tile[32][33];
  const float* ip = in + (size_t)blockIdx.z * R * C;
  bf16* op = out + (size_t)blockIdx.z * R * C;
  int r0 = blockIdx.y * 32, c0 = blockIdx.x * 32;
  int tr = threadIdx.x >> 3;
  int tc = (threadIdx.x & 7) * 4;
  float4 v = *(const float4*)(ip + (size_t)(r0 + tr) * C + c0 + tc);
  tile[tr][tc] = v.x; tile[tr][tc + 1] = v.y; tile[tr][tc + 2] = v.z; tile[tr][tc + 3] = v.w;
  __syncthreads();
  bf16x4 o = {(bf16)tile[tc + 0][tr], (bf16)tile[tc + 1][tr],
              (bf16)tile[tc + 2][tr], (bf16)tile[tc + 3][tr]};
  *(bf16x4*)(op + (size_t)(c0 + tr) * R + r0 + tc) = o;
}

// ------- gating: fp32 logits, softmax, top-2; also emits xb (bf16 copy of x) -------
__global__ void gate_kernel(const float* __restrict__ x, const float* __restrict__ Wg,
                            int2* __restrict__ ge, float2* __restrict__ gp,
                            bf16* __restrict__ xb) {
  int t = blockIdx.x * 4 + (threadIdx.x >> 6);
  int lane = threadIdx.x & 63;
  const float* xr = x + (size_t)t * DDIM;
  bf16* xbr = xb + (size_t)t * DDIM;
  float a[8];
#pragma unroll
  for (int e = 0; e < 8; e++) a[e] = 0.f;
#pragma unroll
  for (int it = 0; it < 4; it++) {
    int d0 = it * 256 + lane * 4;
    float4 xv = *(const float4*)(xr + d0);
    bf16x4 o = {(bf16)xv.x, (bf16)xv.y, (bf16)xv.z, (bf16)xv.w};
    *(bf16x4*)(xbr + d0) = o;
    float xs[4] = {xv.x, xv.y, xv.z, xv.w};
#pragma unroll
    for (int dd = 0; dd < 4; dd++) {
      float4 w0 = *(const float4*)(Wg + (size_t)(d0 + dd) * 8);
      float4 w1 = *(const float4*)(Wg + (size_t)(d0 + dd) * 8 + 4);
      a[0] += xs[dd] * w0.x; a[1] += xs[dd] * w0.y; a[2] += xs[dd] * w0.z; a[3] += xs[dd] * w0.w;
      a[4] += xs[dd] * w1.x; a[5] += xs[dd] * w1.y; a[6] += xs[dd] * w1.z; a[7] += xs[dd] * w1.w;
    }
  }
#pragma unroll
  for (int off = 32; off >= 1; off >>= 1) {
#pragma unroll
    for (int e = 0; e < 8; e++) a[e] += __shfl_xor(a[e], off);
  }
  if (lane == 0) {
    float m = a[0];
#pragma unroll
    for (int e = 1; e < 8; e++) m = fmaxf(m, a[e]);
    float p[8]; float s = 0.f;
#pragma unroll
    for (int e = 0; e < 8; e++) { p[e] = expf(a[e] - m); s += p[e]; }
    float inv = 1.f / s;
    int i0 = 0; float v0 = a[0];
#pragma unroll
    for (int e = 1; e < 8; e++) if (a[e] > v0) { v0 = a[e]; i0 = e; }
    int i1 = -1; float v1 = -1e30f;
#pragma unroll
    for (int e = 0; e < 8; e++) if (e != i0 && a[e] > v1) { v1 = a[e]; i1 = e; }
    ge[t] = make_int2(i0, i1);
    gp[t] = make_float2(p[i0] * inv, p[i1] * inv);
  }
}

// ------- deterministic stable counting sort of 8192 pairs by expert (1 block) -------
// meta[0..8]=segment base, meta[9..16]=tileStart[e] (BM rows/tile), meta[17]=totalTiles
__global__ void sort_kernel(const int2* __restrict__ ge, const float2* __restrict__ gp,
                            int* __restrict__ tok, float* __restrict__ ps,
                            int* __restrict__ meta) {
  __shared__ int hist[8], runn[8], wc[16][8], wb[16][8], baseS[9];
  int tid = threadIdx.x;
  int lane = tid & 63, wv = tid >> 6;
  if (tid < 8) hist[tid] = 0;
  __syncthreads();
  for (int i = tid; i < NPAIR; i += 1024) {
    int2 g = ge[i >> 1];
    int e = (i & 1) ? g.y : g.x;
    atomicAdd(&hist[e], 1);
  }
  __syncthreads();
  if (tid == 0) {
    int b = 0, ts = 0;
    for (int e = 0; e < 8; e++) {
      baseS[e] = b; meta[e] = b; meta[9 + e] = ts;
      b += hist[e]; ts += (hist[e] + BM - 1) / BM;
    }
    baseS[8] = b; meta[8] = b; meta[17] = ts;
  }
  __syncthreads();
  if (tid < 8) runn[tid] = baseS[tid];
  __syncthreads();
  for (int c = 0; c < 8; c++) {
    int i = c * 1024 + tid;
    int2 g = ge[i >> 1];
    int e = (i & 1) ? g.y : g.x;
    int rank = 0;
#pragma unroll
    for (int ee = 0; ee < 8; ee++) {
      unsigned long long b = __ballot(e == ee);
      if (e == ee) rank = __popcll(b & ((1ull << lane) - 1ull));
      if (lane == 0) wc[wv][ee] = __popcll(b);
    }
    __syncthreads();
    if (tid < 8) {
      int s = runn[tid];
      for (int w = 0; w < 16; w++) { wb[w][tid] = s; s += wc[w][tid]; }
      runn[tid] = s;
    }
    __syncthreads();
    int pos = wb[wv][e] + rank;
    tok[pos] = i >> 1;
    float2 p2 = gp[i >> 1];
    ps[pos] = (i & 1) ? p2.y : p2.x;
    __syncthreads();
  }
}

// ---------------- zero out (needed: GEMM2 accumulates into it) ----------------
__global__ void zero_kernel(float4* __restrict__ p) {
  p[blockIdx.x * 256 + threadIdx.x] = make_float4(0.f, 0.f, 0.f, 0.f);
}

// -- grouped GEMM: BM=256, BN=128, BK=32, 512 thr (8 waves 4Mx2N), 2 blocks/CU --
// 3-slot LDS ring (24 KiB/slot = 72 KiB), depth-2 prefetch, counted vmcnt(3),
// one raw s_barrier per K-tile. T2 swizzle: chunk ^= (row>>1)&3 (16B chunks).
// FIRST: A=xb[tok[row]], Bt=W1T -> h = relu(A*B + b1), bf16
// !FIRST: A=h[row],      Bt=W2T -> atomicAdd(out[tok[row]], (A*B + b2) * ps[row])
template <int KDIM, int NPE, bool FIRST>
__global__ __launch_bounds__(512, 4)
void moe_gemm_kernel(const bf16* __restrict__ A, const bf16* __restrict__ Bt,
                     const float* __restrict__ bias, const int* __restrict__ tok,
                     const float* __restrict__ ps, const int* __restrict__ meta,
                     bf16* __restrict__ hout, float* __restrict__ outp, int MT) {
  __shared__ bf16 lds[3][12288];  // per slot: A 8192 elems (256x32), B 4096 (128x32)

  // T1: bijective XCD remap (m204); lin is tileN-major so same-XCD blocks share B panel
  int nwg = gridDim.x;
  int orig = blockIdx.x;
  int q = nwg >> 3, rr8 = nwg & 7;
  int xcd = orig & 7, off8 = orig >> 3;
  int lin = (xcd < rr8 ? xcd * (q + 1) : rr8 * (q + 1) + (xcd - rr8) * q) + off8;
  int tileN = lin / MT;
  int tileM = lin - tileN * MT;
  if (tileM >= meta[17]) return;
  int e = 0;
#pragma unroll
  for (int k = 1; k < 8; k++) if (tileM >= meta[9 + k]) e = k;
  int row0 = meta[e] + (tileM - meta[9 + e]) * BM;
  int segEnd = meta[e + 1];
  int n0 = tileN * BN;

  int t = threadIdx.x;
  // staging: round r (A: r=0,1; B: one round): LDS row r*128+(t>>2), chunk t&3.
  // pre-swizzle SOURCE chunk: c' = (t&3) ^ ((row>>1)&3); (row>>1)&3 == (t>>3)&3
  const bf16* aSrc[2];
  const bf16* bSrc;
  {
    int swz = ((t & 3) ^ ((t >> 3) & 3)) * 8;
#pragma unroll
    for (int r = 0; r < 2; r++) {
      int row = r * 128 + (t >> 2);
      int gRow = row0 + row; if (gRow > NPAIR - 1) gRow = NPAIR - 1;
      int arow = FIRST ? tok[gRow] : gRow;
      aSrc[r] = A + (size_t)arow * KDIM + swz;
    }
    bSrc = Bt + ((size_t)e * NPE + n0 + (t >> 2)) * KDIM + swz;
  }

  int lane = t & 63, wv = t >> 6;
  int wm = wv >> 1, wn = wv & 1;  // 4x2 waves; per-wave out 64x64
  int l15 = lane & 15, l4 = lane >> 4;
  int aOff[4], bOff[4];
#pragma unroll
  for (int m = 0; m < 4; m++) {
    int row = wm * 64 + m * 16 + l15;
    aOff[m] = row * 32 + ((l4 ^ ((row >> 1) & 3)) * 8);
  }
#pragma unroll
  for (int n = 0; n < 4; n++) {
    int row = wn * 64 + n * 16 + l15;
    bOff[n] = 8192 + row * 32 + ((l4 ^ ((row >> 1) & 3)) * 8);
  }

  f32x4 acc[4][4];
#pragma unroll
  for (int m = 0; m < 4; m++)
#pragma unroll
    for (int n = 0; n < 4; n++)
#pragma unroll
      for (int j = 0; j < 4; j++) acc[m][n][j] = 0.f;

  auto STAGE = [&](int kt, int slot) {
    bf16* sb = &lds[slot][0];
    int ko = kt * BK;
    gload16(aSrc[0] + ko, sb + t * 8);
    gload16(aSrc[1] + ko, sb + 4096 + t * 8);
    gload16(bSrc + ko, sb + 8192 + t * 8);
  };

  constexpr int nk = KDIM / BK;
  STAGE(0, 0);
  STAGE(1, 1);
  for (int kt = 0; kt < nk; kt++) {
    // drain tile kt only (3 loads/thread/tile); keep kt+1 (3 loads) in flight
    if (kt == nk - 1) asm volatile("s_waitcnt vmcnt(0)\n\ts_barrier" ::: "memory");
    else              asm volatile("s_waitcnt vmcnt(3)\n\ts_barrier" ::: "memory");
    if (kt + 2 < nk) STAGE(kt + 2, (kt + 2) % 3);  // slot last read at kt-1: safe
    __builtin_amdgcn_sched_barrier(0);
    const bf16* sb = &lds[kt % 3][0];
    bf16x8 af[4], bfr[4];
#pragma unroll
    for (int m = 0; m < 4; m++) af[m] = *(const bf16x8*)(sb + aOff[m]);
#pragma unroll
    for (int n = 0; n < 4; n++) bfr[n] = *(const bf16x8*)(sb + bOff[n]);
    __builtin_amdgcn_s_setprio(1);
#pragma unroll
    for (int m = 0; m < 4; m++)
#pragma unroll
      for (int n = 0; n < 4; n++)
        acc[m][n] = __builtin_amdgcn_mfma_f32_16x16x32_bf16(af[m], bfr[n], acc[m][n], 0, 0, 0);
    __builtin_amdgcn_s_setprio(0);
  }

  int colb = n0 + wn * 64 + l15;
  int rowb = wm * 64 + l4 * 4;
  float bia[4];
#pragma unroll
  for (int n = 0; n < 4; n++) bia[n] = bias[(size_t)e * NPE + colb + n * 16];
#pragma unroll
  for (int m = 0; m < 4; m++) {
#pragma unroll
    for (int j = 0; j < 4; j++) {
      int gRow = row0 + rowb + m * 16 + j;
      if (gRow < segEnd) {
        if (FIRST) {
#pragma unroll
          for (int n = 0; n < 4; n++) {
            float v = acc[m][n][j] + bia[n];
            v = fmaxf(v, 0.f);
            hout[(size_t)gRow * NPE + colb + n * 16] = (bf16)v;
          }
        } else {
          float pscale = ps[gRow];
          float* orow = outp + (size_t)tok[gRow] * DDIM;
#pragma unroll
          for (int n = 0; n < 4; n++) {
            float v = (acc[m][n][j] + bia[n]) * pscale;
            atomicAdd(orow + colb + n * 16, v);  // exactly 2 adds/elem -> deterministic
          }
        }
      }
    }
  }
}

extern "C" void kernel_launch(void* const* d_in, const int* in_sizes, int n_in,
                              void* d_out, int out_size, void* d_ws, size_t ws_size,
                              hipStream_t stream) {
  (void)in_sizes; (void)n_in; (void)ws_size;
  const float* x  = (const float*)d_in[0];
  const float* Wg = (const float*)d_in[1];
  const float* W1 = (const float*)d_in[2];
  const float* b1 = (const float*)d_in[3];
  const float* W2 = (const float*)d_in[4];
  const float* b2 = (const float*)d_in[5];
  float* out = (float*)d_out;

  char* ws = (char*)d_ws;
  bf16*  xb   = (bf16*)(ws);                     //   8 MiB: [4096][1024] bf16
  bf16*  W1T  = (bf16*)(ws + (8ull  << 20));     //  32 MiB: [8][2048][1024] bf16
  bf16*  W2T  = (bf16*)(ws + (40ull << 20));     //  32 MiB: [8][1024][2048] bf16
  bf16*  hbuf = (bf16*)(ws + (72ull << 20));     //  32 MiB: [8192][2048] bf16
  char*  ext  = ws + (104ull << 20);
  int2*   ge      = (int2*)(ext);
  float2* gp      = (float2*)(ext + (64u  << 10));
  int*    tok     = (int*)(ext + (128u << 10));
  float*  psarr   = (float*)(ext + (160u << 10));
  int*    meta    = (int*)(ext + (224u << 10));

  transpose_cvt_kernel<<<dim3(64, 32, 8), 256, 0, stream>>>(W1, W1T, 1024, 2048);
  transpose_cvt_kernel<<<dim3(32, 64, 8), 256, 0, stream>>>(W2, W2T, 2048, 1024);
  gate_kernel<<<1024, 256, 0, stream>>>(x, Wg, ge, gp, xb);
  sort_kernel<<<1, 1024, 0, stream>>>(ge, gp, tok, psarr, meta);
  zero_kernel<<<out_size / 1024, 256, 0, stream>>>((float4*)out);
  moe_gemm_kernel<1024, 2048, true><<<dim3(MTILES * 16), 512, 0, stream>>>(
      xb, W1T, b1, tok, psarr, meta, hbuf, nullptr, MTILES);
  moe_gemm_kernel<2048, 1024, false><<<dim3(MTILES * 8), 512, 0, stream>>>(
      hbuf, W2T, b2, tok, psarr, meta, nullptr, out, MTILES);
}

// Round 5
// 201.390 us; speedup vs baseline: 1.0879x; 1.0879x over previous
//
#include <hip/hip_runtime.h>
#include <hip/hip_bf16.h>
#include <stdint.h>

typedef __bf16 bf16;
typedef __bf16 bf16x8 __attribute__((ext_vector_type(8)));
typedef __bf16 bf16x4 __attribute__((ext_vector_type(4)));
typedef float f32x4 __attribute__((ext_vector_type(4)));

#define N_TOK 4096
#define DDIM 1024
#define HDIM 2048
#define NPAIR 8192
// worst-case tile counts: sum_e ceil(cnt_e/BM)
#define MT128 71
#define MT256 39

__device__ __forceinline__ void gload16(const void* g, void* l) {
  __builtin_amdgcn_global_load_lds(
      (const __attribute__((address_space(1))) unsigned int*)g,
      (__attribute__((address_space(3))) unsigned int*)l, 16, 0, 0);
}

// ------- per-expert transpose+convert: in [R][C] f32 -> out [C][R] bf16 -------
__global__ void transpose_cvt_kernel(const float* __restrict__ in, bf16* __restrict__ out,
                                     int R, int C) {
  __shared__ float tile[32][33];
  const float* ip = in + (size_t)blockIdx.z * R * C;
  bf16* op = out + (size_t)blockIdx.z * R * C;
  int r0 = blockIdx.y * 32, c0 = blockIdx.x * 32;
  int tr = threadIdx.x >> 3;
  int tc = (threadIdx.x & 7) * 4;
  float4 v = *(const float4*)(ip + (size_t)(r0 + tr) * C + c0 + tc);
  tile[tr][tc] = v.x; tile[tr][tc + 1] = v.y; tile[tr][tc + 2] = v.z; tile[tr][tc + 3] = v.w;
  __syncthreads();
  bf16x4 o = {(bf16)tile[tc + 0][tr], (bf16)tile[tc + 1][tr],
              (bf16)tile[tc + 2][tr], (bf16)tile[tc + 3][tr]};
  *(bf16x4*)(op + (size_t)(c0 + tr) * R + r0 + tc) = o;
}

// ------- gating: fp32 logits, softmax, top-2; also emits xb (bf16 copy of x) -------
__global__ void gate_kernel(const float* __restrict__ x, const float* __restrict__ Wg,
                            int2* __restrict__ ge, float2* __restrict__ gp,
                            bf16* __restrict__ xb) {
  int t = blockIdx.x * 4 + (threadIdx.x >> 6);
  int lane = threadIdx.x & 63;
  const float* xr = x + (size_t)t * DDIM;
  bf16* xbr = xb + (size_t)t * DDIM;
  float a[8];
#pragma unroll
  for (int e = 0; e < 8; e++) a[e] = 0.f;
#pragma unroll
  for (int it = 0; it < 4; it++) {
    int d0 = it * 256 + lane * 4;
    float4 xv = *(const float4*)(xr + d0);
    bf16x4 o = {(bf16)xv.x, (bf16)xv.y, (bf16)xv.z, (bf16)xv.w};
    *(bf16x4*)(xbr + d0) = o;
    float xs[4] = {xv.x, xv.y, xv.z, xv.w};
#pragma unroll
    for (int dd = 0; dd < 4; dd++) {
      float4 w0 = *(const float4*)(Wg + (size_t)(d0 + dd) * 8);
      float4 w1 = *(const float4*)(Wg + (size_t)(d0 + dd) * 8 + 4);
      a[0] += xs[dd] * w0.x; a[1] += xs[dd] * w0.y; a[2] += xs[dd] * w0.z; a[3] += xs[dd] * w0.w;
      a[4] += xs[dd] * w1.x; a[5] += xs[dd] * w1.y; a[6] += xs[dd] * w1.z; a[7] += xs[dd] * w1.w;
    }
  }
#pragma unroll
  for (int off = 32; off >= 1; off >>= 1) {
#pragma unroll
    for (int e = 0; e < 8; e++) a[e] += __shfl_xor(a[e], off);
  }
  if (lane == 0) {
    float m = a[0];
#pragma unroll
    for (int e = 1; e < 8; e++) m = fmaxf(m, a[e]);
    float p[8]; float s = 0.f;
#pragma unroll
    for (int e = 0; e < 8; e++) { p[e] = expf(a[e] - m); s += p[e]; }
    float inv = 1.f / s;
    int i0 = 0; float v0 = a[0];
#pragma unroll
    for (int e = 1; e < 8; e++) if (a[e] > v0) { v0 = a[e]; i0 = e; }
    int i1 = -1; float v1 = -1e30f;
#pragma unroll
    for (int e = 0; e < 8; e++) if (e != i0 && a[e] > v1) { v1 = a[e]; i1 = e; }
    ge[t] = make_int2(i0, i1);
    gp[t] = make_float2(p[i0] * inv, p[i1] * inv);
  }
}

// ------- deterministic stable counting sort of 8192 pairs by expert (1 block) -------
// meta[0..8]=segment base; two tile maps:
//   BM=128: meta[9..16]=tileStart, meta[17]=total
//   BM=256: meta[18..25]=tileStart, meta[26]=total
__global__ void sort_kernel(const int2* __restrict__ ge, const float2* __restrict__ gp,
                            int* __restrict__ tok, float* __restrict__ ps,
                            int* __restrict__ meta) {
  __shared__ int hist[8], runn[8], wc[16][8], wb[16][8], baseS[9];
  int tid = threadIdx.x;
  int lane = tid & 63, wv = tid >> 6;
  if (tid < 8) hist[tid] = 0;
  __syncthreads();
  for (int i = tid; i < NPAIR; i += 1024) {
    int2 g = ge[i >> 1];
    int e = (i & 1) ? g.y : g.x;
    atomicAdd(&hist[e], 1);
  }
  __syncthreads();
  if (tid == 0) {
    int b = 0, ts1 = 0, ts2 = 0;
    for (int e = 0; e < 8; e++) {
      baseS[e] = b; meta[e] = b;
      meta[9 + e] = ts1;  ts1 += (hist[e] + 127) / 128;
      meta[18 + e] = ts2; ts2 += (hist[e] + 255) / 256;
      b += hist[e];
    }
    baseS[8] = b; meta[8] = b; meta[17] = ts1; meta[26] = ts2;
  }
  __syncthreads();
  if (tid < 8) runn[tid] = baseS[tid];
  __syncthreads();
  for (int c = 0; c < 8; c++) {
    int i = c * 1024 + tid;
    int2 g = ge[i >> 1];
    int e = (i & 1) ? g.y : g.x;
    int rank = 0;
#pragma unroll
    for (int ee = 0; ee < 8; ee++) {
      unsigned long long b = __ballot(e == ee);
      if (e == ee) rank = __popcll(b & ((1ull << lane) - 1ull));
      if (lane == 0) wc[wv][ee] = __popcll(b);
    }
    __syncthreads();
    if (tid < 8) {
      int s = runn[tid];
      for (int w = 0; w < 16; w++) { wb[w][tid] = s; s += wc[w][tid]; }
      runn[tid] = s;
    }
    __syncthreads();
    int pos = wb[wv][e] + rank;
    tok[pos] = i >> 1;
    float2 p2 = gp[i >> 1];
    ps[pos] = (i & 1) ? p2.y : p2.x;
    __syncthreads();
  }
}

// ---------------- zero out (needed: GEMM2 accumulates into it) ----------------
__global__ void zero_kernel(float4* __restrict__ p) {
  p[blockIdx.x * 256 + threadIdx.x] = make_float4(0.f, 0.f, 0.f, 0.f);
}

// ---------------- grouped GEMM, unified template ----------------
// BK=32, 3-slot LDS ring, depth-2 prefetch, counted vmcnt(LOADS), one raw
// s_barrier per K-tile, T2 16B-chunk swizzle via pre-swizzled global source.
// XCD-chunked tile order: tileM ranges partitioned across 8 XCDs using the
// RUNTIME tile count; within an XCD, tileM varies fastest (B-panel shared by
// consecutive blocks; the XCD's A-range stays L2-resident across tileN sweeps).
// FIRST: A=xb[tok[row]], Bt=W1T -> h = relu(A*B + b1), bf16
// !FIRST: A=h[row],      Bt=W2T -> atomicAdd(out[tok[row]], (A*B + b2)*ps[row])
template <int KDIM, int NPE, bool FIRST, int BMT, int THREADS, int NT, int MAPOFF>
__global__ __launch_bounds__(THREADS, (THREADS == 256) ? 3 : 4)
void moe_gemm_kernel(const bf16* __restrict__ A, const bf16* __restrict__ Bt,
                     const float* __restrict__ bias, const int* __restrict__ tok,
                     const float* __restrict__ ps, const int* __restrict__ meta,
                     bf16* __restrict__ hout, float* __restrict__ outp) {
  constexpr int AR = BMT * 4 / THREADS;     // A staging rounds (2)
  constexpr int BR = 128 * 4 / THREADS;     // B staging rounds (2 or 1)
  constexpr int SLOT = (BMT + 128) * 32;    // LDS elems per slot
  __shared__ bf16 lds[3][SLOT];

  // runtime-balanced XCD-chunked mapping
  int MTa = meta[MAPOFF + 8];
  int xcd = blockIdx.x & 7;
  int idx = blockIdx.x >> 3;
  int mLo = (MTa * xcd) >> 3;
  int mHi = (MTa * (xcd + 1)) >> 3;
  int cnt = mHi - mLo;
  if (idx >= cnt * NT) return;
  int tileN = idx / cnt;
  int tileM = mLo + idx - tileN * cnt;

  int e = 0;
#pragma unroll
  for (int k = 1; k < 8; k++) if (tileM >= meta[MAPOFF + k]) e = k;
  int row0 = meta[e] + (tileM - meta[MAPOFF + e]) * BMT;
  int segEnd = meta[e + 1];
  int n0 = tileN * 128;

  int t = threadIdx.x;
  // staging: round r -> LDS row r*(THREADS/4)+(t>>2), dest 16B-chunk t&3.
  // pre-swizzle SOURCE chunk: c' = (t&3) ^ ((row>>1)&3); (row>>1)&3 == (t>>3)&3
  const bf16* aSrc[AR];
  const bf16* bSrc[BR];
  {
    int swz = ((t & 3) ^ ((t >> 3) & 3)) * 8;
#pragma unroll
    for (int r = 0; r < AR; r++) {
      int row = r * (THREADS / 4) + (t >> 2);
      int gRow = row0 + row; if (gRow > NPAIR - 1) gRow = NPAIR - 1;
      int arow = FIRST ? tok[gRow] : gRow;
      aSrc[r] = A + (size_t)arow * KDIM + swz;
    }
#pragma unroll
    for (int r = 0; r < BR; r++) {
      int row = r * (THREADS / 4) + (t >> 2);
      bSrc[r] = Bt + ((size_t)e * NPE + n0 + row) * KDIM + swz;
    }
  }

  int lane = t & 63, wv = t >> 6;
  int wm = wv >> 1, wn = wv & 1;  // per-wave out 64x64
  int l15 = lane & 15, l4 = lane >> 4;
  int aOff[4], bOff[4];
#pragma unroll
  for (int m = 0; m < 4; m++) {
    int row = wm * 64 + m * 16 + l15;
    aOff[m] = row * 32 + ((l4 ^ ((row >> 1) & 3)) * 8);
  }
#pragma unroll
  for (int n = 0; n < 4; n++) {
    int row = wn * 64 + n * 16 + l15;
    bOff[n] = BMT * 32 + row * 32 + ((l4 ^ ((row >> 1) & 3)) * 8);
  }

  f32x4 acc[4][4];
#pragma unroll
  for (int m = 0; m < 4; m++)
#pragma unroll
    for (int n = 0; n < 4; n++)
#pragma unroll
      for (int j = 0; j < 4; j++) acc[m][n][j] = 0.f;

  auto STAGE = [&](int kt, int slot) {
    bf16* sb = &lds[slot][0];
    int ko = kt * 32;
#pragma unroll
    for (int r = 0; r < AR; r++) gload16(aSrc[r] + ko, sb + (r * THREADS + t) * 8);
#pragma unroll
    for (int r = 0; r < BR; r++) gload16(bSrc[r] + ko, sb + BMT * 32 + (r * THREADS + t) * 8);
  };

  constexpr int nk = KDIM / 32;
  STAGE(0, 0);
  STAGE(1, 1);
  for (int kt = 0; kt < nk; kt++) {
    // drain tile kt only (AR+BR loads/thread/tile); keep next tile in flight
    if (kt == nk - 1) asm volatile("s_waitcnt vmcnt(0)\n\ts_barrier" ::: "memory");
    else if constexpr (AR + BR == 4) asm volatile("s_waitcnt vmcnt(4)\n\ts_barrier" ::: "memory");
    else                             asm volatile("s_waitcnt vmcnt(3)\n\ts_barrier" ::: "memory");
    if (kt + 2 < nk) STAGE(kt + 2, (kt + 2) % 3);  // slot last read at kt-1: safe
    __builtin_amdgcn_sched_barrier(0);
    const bf16* sb = &lds[kt % 3][0];
    bf16x8 af[4], bfr[4];
#pragma unroll
    for (int m = 0; m < 4; m++) af[m] = *(const bf16x8*)(sb + aOff[m]);
#pragma unroll
    for (int n = 0; n < 4; n++) bfr[n] = *(const bf16x8*)(sb + bOff[n]);
    __builtin_amdgcn_s_setprio(1);
#pragma unroll
    for (int m = 0; m < 4; m++)
#pragma unroll
      for (int n = 0; n < 4; n++)
        acc[m][n] = __builtin_amdgcn_mfma_f32_16x16x32_bf16(af[m], bfr[n], acc[m][n], 0, 0, 0);
    __builtin_amdgcn_s_setprio(0);
  }

  int colb = n0 + wn * 64 + l15;
  int rowb = wm * 64 + l4 * 4;
  float bia[4];
#pragma unroll
  for (int n = 0; n < 4; n++) bia[n] = bias[(size_t)e * NPE + colb + n * 16];
#pragma unroll
  for (int m = 0; m < 4; m++) {
#pragma unroll
    for (int j = 0; j < 4; j++) {
      int gRow = row0 + rowb + m * 16 + j;
      if (gRow < segEnd) {
        if (FIRST) {
#pragma unroll
          for (int n = 0; n < 4; n++) {
            float v = acc[m][n][j] + bia[n];
            v = fmaxf(v, 0.f);
            hout[(size_t)gRow * NPE + colb + n * 16] = (bf16)v;
          }
        } else {
          float pscale = ps[gRow];
          float* orow = outp + (size_t)tok[gRow] * DDIM;
#pragma unroll
          for (int n = 0; n < 4; n++) {
            float v = (acc[m][n][j] + bia[n]) * pscale;
            atomicAdd(orow + colb + n * 16, v);  // exactly 2 adds/elem -> deterministic
          }
        }
      }
    }
  }
}

extern "C" void kernel_launch(void* const* d_in, const int* in_sizes, int n_in,
                              void* d_out, int out_size, void* d_ws, size_t ws_size,
                              hipStream_t stream) {
  (void)in_sizes; (void)n_in; (void)ws_size;
  const float* x  = (const float*)d_in[0];
  const float* Wg = (const float*)d_in[1];
  const float* W1 = (const float*)d_in[2];
  const float* b1 = (const float*)d_in[3];
  const float* W2 = (const float*)d_in[4];
  const float* b2 = (const float*)d_in[5];
  float* out = (float*)d_out;

  char* ws = (char*)d_ws;
  bf16*  xb   = (bf16*)(ws);                     //   8 MiB: [4096][1024] bf16
  bf16*  W1T  = (bf16*)(ws + (8ull  << 20));     //  32 MiB: [8][2048][1024] bf16
  bf16*  W2T  = (bf16*)(ws + (40ull << 20));     //  32 MiB: [8][1024][2048] bf16
  bf16*  hbuf = (bf16*)(ws + (72ull << 20));     //  32 MiB: [8192][2048] bf16
  char*  ext  = ws + (104ull << 20);
  int2*   ge      = (int2*)(ext);
  float2* gp      = (float2*)(ext + (64u  << 10));
  int*    tok     = (int*)(ext + (128u << 10));
  float*  psarr   = (float*)(ext + (160u << 10));
  int*    meta    = (int*)(ext + (224u << 10));

  transpose_cvt_kernel<<<dim3(64, 32, 8), 256, 0, stream>>>(W1, W1T, 1024, 2048);
  transpose_cvt_kernel<<<dim3(32, 64, 8), 256, 0, stream>>>(W2, W2T, 2048, 1024);
  gate_kernel<<<1024, 256, 0, stream>>>(x, Wg, ge, gp, xb);
  sort_kernel<<<1, 1024, 0, stream>>>(ge, gp, tok, psarr, meta);
  zero_kernel<<<out_size / 1024, 256, 0, stream>>>((float4*)out);
  // G1: BM=128, 256 thr, NT=16; per-XCD slots = ceil(71/8)=9 -> 9*16*8 = 1152 blocks
  moe_gemm_kernel<1024, 2048, true, 128, 256, 16, 9><<<dim3(1152), 256, 0, stream>>>(
      xb, W1T, b1, tok, psarr, meta, hbuf, nullptr);
  // G2: BM=256, 512 thr, NT=8; per-XCD slots = ceil(39/8)=5 -> 5*8*8 = 320 blocks
  moe_gemm_kernel<2048, 1024, false, 256, 512, 8, 18><<<dim3(320), 512, 0, stream>>>(
      hbuf, W2T, b2, tok, psarr, meta, nullptr, out);
}

// Round 6
// 197.769 us; speedup vs baseline: 1.1078x; 1.0183x over previous
//
#include <hip/hip_runtime.h>
#include <hip/hip_bf16.h>
#include <stdint.h>

typedef __bf16 bf16;
typedef __bf16 bf16x8 __attribute__((ext_vector_type(8)));
typedef __bf16 bf16x4 __attribute__((ext_vector_type(4)));
typedef float f32x4 __attribute__((ext_vector_type(4)));

#define N_TOK 4096
#define DDIM 1024
#define HDIM 2048
#define NPAIR 8192

__device__ __forceinline__ void gload16(const void* g, void* l) {
  __builtin_amdgcn_global_load_lds(
      (const __attribute__((address_space(1))) unsigned int*)g,
      (__attribute__((address_space(3))) unsigned int*)l, 16, 0, 0);
}

// ------- per-expert transpose+convert: in [R][C] f32 -> out [C][R] bf16 -------
__global__ void transpose_cvt_kernel(const float* __restrict__ in, bf16* __restrict__ out,
                                     int R, int C) {
  __shared__ float tile[32][33];
  const float* ip = in + (size_t)blockIdx.z * R * C;
  bf16* op = out + (size_t)blockIdx.z * R * C;
  int r0 = blockIdx.y * 32, c0 = blockIdx.x * 32;
  int tr = threadIdx.x >> 3;
  int tc = (threadIdx.x & 7) * 4;
  float4 v = *(const float4*)(ip + (size_t)(r0 + tr) * C + c0 + tc);
  tile[tr][tc] = v.x; tile[tr][tc + 1] = v.y; tile[tr][tc + 2] = v.z; tile[tr][tc + 3] = v.w;
  __syncthreads();
  bf16x4 o = {(bf16)tile[tc + 0][tr], (bf16)tile[tc + 1][tr],
              (bf16)tile[tc + 2][tr], (bf16)tile[tc + 3][tr]};
  *(bf16x4*)(op + (size_t)(c0 + tr) * R + r0 + tc) = o;
}

// -- gating: fp32 logits, softmax, top-2; emits xb (bf16 x) and zeroes out rows --
__global__ void gate_kernel(const float* __restrict__ x, const float* __restrict__ Wg,
                            int2* __restrict__ ge, float2* __restrict__ gp,
                            bf16* __restrict__ xb, float* __restrict__ outp) {
  int t0 = blockIdx.x * 4;
  // zero the 4 out rows this block owns (GEMM2 accumulates atomically into out)
  {
    float4 z = make_float4(0.f, 0.f, 0.f, 0.f);
    float4* ob = (float4*)(outp + (size_t)t0 * DDIM);
#pragma unroll
    for (int r = 0; r < 4; r++) ob[r * 256 + threadIdx.x] = z;
  }
  int t = t0 + (threadIdx.x >> 6);
  int lane = threadIdx.x & 63;
  const float* xr = x + (size_t)t * DDIM;
  bf16* xbr = xb + (size_t)t * DDIM;
  float a[8];
#pragma unroll
  for (int e = 0; e < 8; e++) a[e] = 0.f;
#pragma unroll
  for (int it = 0; it < 4; it++) {
    int d0 = it * 256 + lane * 4;
    float4 xv = *(const float4*)(xr + d0);
    bf16x4 o = {(bf16)xv.x, (bf16)xv.y, (bf16)xv.z, (bf16)xv.w};
    *(bf16x4*)(xbr + d0) = o;
    float xs[4] = {xv.x, xv.y, xv.z, xv.w};
#pragma unroll
    for (int dd = 0; dd < 4; dd++) {
      float4 w0 = *(const float4*)(Wg + (size_t)(d0 + dd) * 8);
      float4 w1 = *(const float4*)(Wg + (size_t)(d0 + dd) * 8 + 4);
      a[0] += xs[dd] * w0.x; a[1] += xs[dd] * w0.y; a[2] += xs[dd] * w0.z; a[3] += xs[dd] * w0.w;
      a[4] += xs[dd] * w1.x; a[5] += xs[dd] * w1.y; a[6] += xs[dd] * w1.z; a[7] += xs[dd] * w1.w;
    }
  }
#pragma unroll
  for (int off = 32; off >= 1; off >>= 1) {
#pragma unroll
    for (int e = 0; e < 8; e++) a[e] += __shfl_xor(a[e], off);
  }
  if (lane == 0) {
    float m = a[0];
#pragma unroll
    for (int e = 1; e < 8; e++) m = fmaxf(m, a[e]);
    float p[8]; float s = 0.f;
#pragma unroll
    for (int e = 0; e < 8; e++) { p[e] = expf(a[e] - m); s += p[e]; }
    float inv = 1.f / s;
    int i0 = 0; float v0 = a[0];
#pragma unroll
    for (int e = 1; e < 8; e++) if (a[e] > v0) { v0 = a[e]; i0 = e; }
    int i1 = -1; float v1 = -1e30f;
#pragma unroll
    for (int e = 0; e < 8; e++) if (e != i0 && a[e] > v1) { v1 = a[e]; i1 = e; }
    ge[t] = make_int2(i0, i1);
    gp[t] = make_float2(p[i0] * inv, p[i1] * inv);
  }
}

// ------- deterministic stable counting sort of 8192 pairs by expert (1 block) -------
// meta[0..8]=segment base; meta[9..16]=tileStart (BM=128), meta[17]=total128
__global__ void sort_kernel(const int2* __restrict__ ge, const float2* __restrict__ gp,
                            int* __restrict__ tok, float* __restrict__ ps,
                            int* __restrict__ meta) {
  __shared__ int hist[8], runn[8], wc[16][8], wb[16][8], baseS[9];
  int tid = threadIdx.x;
  int lane = tid & 63, wv = tid >> 6;
  if (tid < 8) hist[tid] = 0;
  __syncthreads();
  for (int i = tid; i < NPAIR; i += 1024) {
    int2 g = ge[i >> 1];
    int e = (i & 1) ? g.y : g.x;
    atomicAdd(&hist[e], 1);
  }
  __syncthreads();
  if (tid == 0) {
    int b = 0, ts1 = 0;
    for (int e = 0; e < 8; e++) {
      baseS[e] = b; meta[e] = b;
      meta[9 + e] = ts1;  ts1 += (hist[e] + 127) / 128;
      b += hist[e];
    }
    baseS[8] = b; meta[8] = b; meta[17] = ts1;
  }
  __syncthreads();
  if (tid < 8) runn[tid] = baseS[tid];
  __syncthreads();
  for (int c = 0; c < 8; c++) {
    int i = c * 1024 + tid;
    int2 g = ge[i >> 1];
    int e = (i & 1) ? g.y : g.x;
    int rank = 0;
#pragma unroll
    for (int ee = 0; ee < 8; ee++) {
      unsigned long long b = __ballot(e == ee);
      if (e == ee) rank = __popcll(b & ((1ull << lane) - 1ull));
      if (lane == 0) wc[wv][ee] = __popcll(b);
    }
    __syncthreads();
    if (tid < 8) {
      int s = runn[tid];
      for (int w = 0; w < 16; w++) { wb[w][tid] = s; s += wc[w][tid]; }
      runn[tid] = s;
    }
    __syncthreads();
    int pos = wb[wv][e] + rank;
    tok[pos] = i >> 1;
    float2 p2 = gp[i >> 1];
    ps[pos] = (i & 1) ? p2.y : p2.x;
    __syncthreads();
  }
}

// ---- grouped GEMM: BM=128, BN=128, BK=32, 256 thr (4 waves 2x2), 3 blocks/CU ----
// 3-slot LDS ring (16 KiB/slot), depth-2 prefetch, counted vmcnt(4), one raw
// s_barrier per K-tile, T2 16B-chunk swizzle via pre-swizzled global source.
// XCD-chunked tile order: tileM ranges partitioned across 8 XCDs at RUNTIME;
// within an XCD tileM varies fastest (B-panel shared; A-range stays L2-resident).
// FIRST: A=xb[tok[row]], Bt=W1T -> h = relu(A*B + b1), bf16
// !FIRST: A=h[row],      Bt=W2T -> atomicAdd(out[tok[row]], (A*B + b2)*ps[row])
template <int KDIM, int NPE, bool FIRST, int NT>
__global__ __launch_bounds__(256, 3)
void moe_gemm_kernel(const bf16* __restrict__ A, const bf16* __restrict__ Bt,
                     const float* __restrict__ bias, const int* __restrict__ tok,
                     const float* __restrict__ ps, const int* __restrict__ meta,
                     bf16* __restrict__ hout, float* __restrict__ outp) {
  __shared__ bf16 lds[3][8192];  // per slot: A 4096 elems (128x32), B 4096 (128x32)

  // runtime-balanced XCD-chunked mapping
  int MTa = meta[17];
  int xcd = blockIdx.x & 7;
  int idx = blockIdx.x >> 3;
  int mLo = (MTa * xcd) >> 3;
  int mHi = (MTa * (xcd + 1)) >> 3;
  int cnt = mHi - mLo;
  if (idx >= cnt * NT) return;
  int tileN = idx / cnt;
  int tileM = mLo + idx - tileN * cnt;

  int e = 0;
#pragma unroll
  for (int k = 1; k < 8; k++) if (tileM >= meta[9 + k]) e = k;
  int row0 = meta[e] + (tileM - meta[9 + e]) * 128;
  int segEnd = meta[e + 1];
  int n0 = tileN * 128;

  int t = threadIdx.x;
  // staging: round r -> LDS row r*64+(t>>2), dest 16B-chunk t&3.
  // pre-swizzle SOURCE chunk: c' = (t&3) ^ ((row>>1)&3); (row>>1)&3 == (t>>3)&3
  const bf16* aSrc[2];
  const bf16* bSrc[2];
  {
    int swz = ((t & 3) ^ ((t >> 3) & 3)) * 8;
#pragma unroll
    for (int r = 0; r < 2; r++) {
      int row = r * 64 + (t >> 2);
      int gRow = row0 + row; if (gRow > NPAIR - 1) gRow = NPAIR - 1;
      int arow = FIRST ? tok[gRow] : gRow;
      aSrc[r] = A + (size_t)arow * KDIM + swz;
      bSrc[r] = Bt + ((size_t)e * NPE + n0 + row) * KDIM + swz;
    }
  }

  int lane = t & 63, wv = t >> 6;
  int wm = wv >> 1, wn = wv & 1;  // 2x2 waves; per-wave out 64x64
  int l15 = lane & 15, l4 = lane >> 4;
  int aOff[4], bOff[4];
#pragma unroll
  for (int m = 0; m < 4; m++) {
    int row = wm * 64 + m * 16 + l15;
    aOff[m] = row * 32 + ((l4 ^ ((row >> 1) & 3)) * 8);
  }
#pragma unroll
  for (int n = 0; n < 4; n++) {
    int row = wn * 64 + n * 16 + l15;
    bOff[n] = 4096 + row * 32 + ((l4 ^ ((row >> 1) & 3)) * 8);
  }

  f32x4 acc[4][4];
#pragma unroll
  for (int m = 0; m < 4; m++)
#pragma unroll
    for (int n = 0; n < 4; n++)
#pragma unroll
      for (int j = 0; j < 4; j++) acc[m][n][j] = 0.f;

  auto STAGE = [&](int kt, int slot) {
    bf16* sb = &lds[slot][0];
    int ko = kt * 32;
    gload16(aSrc[0] + ko, sb + t * 8);
    gload16(aSrc[1] + ko, sb + 2048 + t * 8);
    gload16(bSrc[0] + ko, sb + 4096 + t * 8);
    gload16(bSrc[1] + ko, sb + 6144 + t * 8);
  };

  constexpr int nk = KDIM / 32;
  STAGE(0, 0);
  STAGE(1, 1);
  for (int kt = 0; kt < nk; kt++) {
    // drain tile kt only (4 loads/thread/tile); keep kt+1 in flight
    if (kt == nk - 1) asm volatile("s_waitcnt vmcnt(0)\n\ts_barrier" ::: "memory");
    else              asm volatile("s_waitcnt vmcnt(4)\n\ts_barrier" ::: "memory");
    if (kt + 2 < nk) STAGE(kt + 2, (kt + 2) % 3);  // slot last read at kt-1: safe
    __builtin_amdgcn_sched_barrier(0);
    const bf16* sb = &lds[kt % 3][0];
    bf16x8 af[4], bfr[4];
#pragma unroll
    for (int m = 0; m < 4; m++) af[m] = *(const bf16x8*)(sb + aOff[m]);
#pragma unroll
    for (int n = 0; n < 4; n++) bfr[n] = *(const bf16x8*)(sb + bOff[n]);
    __builtin_amdgcn_s_setprio(1);
#pragma unroll
    for (int m = 0; m < 4; m++)
#pragma unroll
      for (int n = 0; n < 4; n++)
        acc[m][n] = __builtin_amdgcn_mfma_f32_16x16x32_bf16(af[m], bfr[n], acc[m][n], 0, 0, 0);
    __builtin_amdgcn_s_setprio(0);
  }

  int colb = n0 + wn * 64 + l15;
  int rowb = wm * 64 + l4 * 4;
  float bia[4];
#pragma unroll
  for (int n = 0; n < 4; n++) bia[n] = bias[(size_t)e * NPE + colb + n * 16];
#pragma unroll
  for (int m = 0; m < 4; m++) {
#pragma unroll
    for (int j = 0; j < 4; j++) {
      int gRow = row0 + rowb + m * 16 + j;
      if (gRow < segEnd) {
        if (FIRST) {
#pragma unroll
          for (int n = 0; n < 4; n++) {
            float v = acc[m][n][j] + bia[n];
            v = fmaxf(v, 0.f);
            hout[(size_t)gRow * NPE + colb + n * 16] = (bf16)v;
          }
        } else {
          float pscale = ps[gRow];
          float* orow = outp + (size_t)tok[gRow] * DDIM;
#pragma unroll
          for (int n = 0; n < 4; n++) {
            float v = (acc[m][n][j] + bia[n]) * pscale;
            atomicAdd(orow + colb + n * 16, v);  // exactly 2 adds/elem -> deterministic
          }
        }
      }
    }
  }
}

extern "C" void kernel_launch(void* const* d_in, const int* in_sizes, int n_in,
                              void* d_out, int out_size, void* d_ws, size_t ws_size,
                              hipStream_t stream) {
  (void)in_sizes; (void)n_in; (void)out_size; (void)ws_size;
  const float* x  = (const float*)d_in[0];
  const float* Wg = (const float*)d_in[1];
  const float* W1 = (const float*)d_in[2];
  const float* b1 = (const float*)d_in[3];
  const float* W2 = (const float*)d_in[4];
  const float* b2 = (const float*)d_in[5];
  float* out = (float*)d_out;

  char* ws = (char*)d_ws;
  bf16*  xb   = (bf16*)(ws);                     //   8 MiB: [4096][1024] bf16
  bf16*  W1T  = (bf16*)(ws + (8ull  << 20));     //  32 MiB: [8][2048][1024] bf16
  bf16*  W2T  = (bf16*)(ws + (40ull << 20));     //  32 MiB: [8][1024][2048] bf16
  bf16*  hbuf = (bf16*)(ws + (72ull << 20));     //  32 MiB: [8192][2048] bf16
  char*  ext  = ws + (104ull << 20);
  int2*   ge      = (int2*)(ext);
  float2* gp      = (float2*)(ext + (64u  << 10));
  int*    tok     = (int*)(ext + (128u << 10));
  float*  psarr   = (float*)(ext + (160u << 10));
  int*    meta    = (int*)(ext + (224u << 10));

  transpose_cvt_kernel<<<dim3(64, 32, 8), 256, 0, stream>>>(W1, W1T, 1024, 2048);
  transpose_cvt_kernel<<<dim3(32, 64, 8), 256, 0, stream>>>(W2, W2T, 2048, 1024);
  gate_kernel<<<1024, 256, 0, stream>>>(x, Wg, ge, gp, xb, out);
  sort_kernel<<<1, 1024, 0, stream>>>(ge, gp, tok, psarr, meta);
  // per-XCD M-slots = ceil(71/8) = 9
  // G1: NT=16 (HDIM/128) -> grid 9*16*8 = 1152
  moe_gemm_kernel<1024, 2048, true, 16><<<dim3(1152), 256, 0, stream>>>(
      xb, W1T, b1, tok, psarr, meta, hbuf, nullptr);
  // G2: NT=8 (DDIM/128) -> grid 9*8*8 = 576
  moe_gemm_kernel<2048, 1024, false, 8><<<dim3(576), 256, 0, stream>>>(
      hbuf, W2T, b2, tok, psarr, meta, nullptr, out);
}